// Round 2
// baseline (780.219 us; speedup 1.0000x reference)
//
#include <hip/hip_runtime.h>

typedef short bf16x8 __attribute__((ext_vector_type(8)));
typedef float f32x4 __attribute__((ext_vector_type(4)));

__device__ inline unsigned short f2bf(float f) {
    union { float f; unsigned u; } v; v.f = f;
    unsigned u = v.u;
    u += 0x7fffu + ((u >> 16) & 1u);   // RNE
    return (unsigned short)(u >> 16);
}

#define KPAD 264   // 256 + 8 bf16 pad -> 2-way bank aliasing only (free)
#define GPB  4     // token-groups per persistent block
#define NBLK 512   // grid: exactly 2 blocks/CU on 256 CUs

// Swizzle W (fp32 [256][256] row-major) -> bf16 MFMA A-fragment order:
// wsw[((mt*8+ks)*64 + lane)*8 + jj] = W[mt*16 + (lane&15)][ks*32 + (lane>>4)*8 + jj]
__global__ void prep_weights(const float* __restrict__ wl,
                             const float* __restrict__ wr,
                             const float* __restrict__ wo,
                             unsigned short* __restrict__ wsw) {
    int idx = blockIdx.x * 256 + threadIdx.x;   // 0 .. 196607
    int w    = idx >> 16;
    int e    = idx & 65535;
    int jj   = e & 7;
    int lane = (e >> 3) & 63;
    int kmt  = e >> 9;          // mt*8 + ks
    int ks   = kmt & 7;
    int mt   = kmt >> 3;
    int row = mt * 16 + (lane & 15);
    int col = ks * 32 + (lane >> 4) * 8 + jj;
    const float* src = (w == 0) ? wl : (w == 1) ? wr : wo;
    wsw[idx] = f2bf(src[row * 256 + col]);
}

// Persistent: 512 blocks (2/CU), each processes GPB=4 token-groups of 16 tokens.
// T14 async-stage: next group's x_l is prefetched into 24 VGPRs before stage1
// (streams under ~10us of compute), x_r mid-epilogue after half the accs die.
// Stores drain under the NEXT iteration's compute (never waited on).
__global__ __launch_bounds__(512, 4) void fused_kernel(
    const float* __restrict__ xl_g, const float* __restrict__ xr_g,
    const unsigned short* __restrict__ wsw, float* __restrict__ out) {

    // LDS states per iteration: XB_l [48][KPAD] @0, XB_r @12672 (bf16) ->
    // P [144][KPAD] overlays @0 -> epilogue scratch 8 waves x 9472 B overlays P.
    __shared__ __align__(16) unsigned short lds[38016];

    const int tid  = threadIdx.x;
    const int wave = tid >> 6;
    const int lane = tid & 63;
    const int q    = lane >> 4;
    const int l15  = lane & 15;

    const float4* L4 = (const float4*)xl_g;
    const float4* R4 = (const float4*)xr_g;
    const bf16x8* wlf = (const bf16x8*)(wsw);
    const bf16x8* wrf = (const bf16x8*)(wsw + 65536);
    const bf16x8* wof = (const bf16x8*)(wsw + 131072);

    int g = blockIdx.x;                      // group index, stride NBLK per iter
    float4 preL[6], preR[6];                 // statically indexed only (no scratch)
    {
        const size_t base = (size_t)g * 3072;
        #pragma unroll
        for (int u = 0; u < 6; ++u) preL[u] = L4[base + u * 512 + tid];
        #pragma unroll
        for (int u = 0; u < 6; ++u) preR[u] = R4[base + u * 512 + tid];
    }

    for (int itg = 0; itg < GPB; ++itg) {
        const int gn = g + NBLK;             // next group (loads guarded on last iter)
        const size_t nbase = (size_t)gn * 3072;

        // ---- Stage 0: prefetched regs -> LDS, fp32 -> bf16, c = i*16 + t ----
        #pragma unroll
        for (int a = 0; a < 2; ++a) {
            unsigned short* dst = lds + a * 12672;
            #pragma unroll
            for (int u = 0; u < 6; ++u) {
                float4 v = a ? preR[u] : preL[u];
                int g4 = u * 512 + tid;
                int gi = g4 * 4;             // 768 % 4 == 0: never straddles a token
                int tok = gi / 768;
                int m0 = gi - tok * 768;
                float vv[4] = {v.x, v.y, v.z, v.w};
                #pragma unroll
                for (int e = 0; e < 4; ++e) {
                    int mm = m0 + e;
                    int I = mm / 3;
                    int i = mm - I * 3;
                    dst[(i * 16 + tok) * KPAD + I] = f2bf(vv[e]);
                }
            }
        }
        __syncthreads();

        // Issue next-group L prefetch NOW: streams under stage1/P/stage2.
        if (itg != GPB - 1) {
            #pragma unroll
            for (int u = 0; u < 6; ++u) preL[u] = L4[nbase + u * 512 + tid];
        }

        // ---- Stage 1: xl = W_l * x_l, xr = W_r * x_r (two M-tiles per wave) ----
        f32x4 accL[2][3] = {};
        f32x4 accR[2][3] = {};
        #pragma unroll
        for (int k = 0; k < 8; ++k) {
            const int koff = k * 32 + q * 8;
            bf16x8 bl[3], br[3];
            #pragma unroll
            for (int nt = 0; nt < 3; ++nt) {
                bl[nt] = *(const bf16x8*)&lds[(nt * 16 + l15) * KPAD + koff];
                br[nt] = *(const bf16x8*)&lds[12672 + (nt * 16 + l15) * KPAD + koff];
            }
            #pragma unroll
            for (int m = 0; m < 2; ++m) {
                const int mt = wave * 2 + m;
                bf16x8 al = wlf[(mt * 8 + k) * 64 + lane];
                bf16x8 ar = wrf[(mt * 8 + k) * 64 + lane];
                #pragma unroll
                for (int nt = 0; nt < 3; ++nt) {
                    accL[m][nt] = __builtin_amdgcn_mfma_f32_16x16x32_bf16(al, bl[nt], accL[m][nt], 0, 0, 0);
                    accR[m][nt] = __builtin_amdgcn_mfma_f32_16x16x32_bf16(ar, br[nt], accR[m][nt], 0, 0, 0);
                }
            }
        }
        __syncthreads();   // all stage-1 LDS reads done; P may overlay XB

        // ---- P build: outer product in regs, write bf16 P[c=(i*3+j)*16+t][r] ----
        #pragma unroll
        for (int m = 0; m < 2; ++m) {
            const int mt = wave * 2 + m;
            const int r0 = mt * 16 + q * 4;
            #pragma unroll
            for (int i = 0; i < 3; ++i) {
                #pragma unroll
                for (int j = 0; j < 3; ++j) {
                    const int c = (i * 3 + j) * 16 + l15;
                    unsigned short h[4];
                    #pragma unroll
                    for (int reg = 0; reg < 4; ++reg)
                        h[reg] = f2bf(accL[m][i][reg] * accR[m][j][reg]);
                    uint2 pk;
                    pk.x = (unsigned)h[0] | ((unsigned)h[1] << 16);
                    pk.y = (unsigned)h[2] | ((unsigned)h[3] << 16);
                    *(uint2*)&lds[c * KPAD + r0] = pk;   // 8B aligned
                }
            }
        }
        __syncthreads();

        // ---- Stage 2: out = W_o * P (256 x 256 x 144), two k-passes ----
        f32x4 accA[2][5] = {};
        f32x4 accB[2][4] = {};
        #pragma unroll
        for (int k = 0; k < 8; ++k) {
            const int koff = k * 32 + q * 8;
            bf16x8 pf[5];
            #pragma unroll
            for (int p = 0; p < 5; ++p)
                pf[p] = *(const bf16x8*)&lds[(p * 16 + l15) * KPAD + koff];
            #pragma unroll
            for (int m = 0; m < 2; ++m) {
                const int mt = wave * 2 + m;
                bf16x8 ao = wof[(mt * 8 + k) * 64 + lane];
                #pragma unroll
                for (int p = 0; p < 5; ++p)
                    accA[m][p] = __builtin_amdgcn_mfma_f32_16x16x32_bf16(ao, pf[p], accA[m][p], 0, 0, 0);
            }
        }
        #pragma unroll
        for (int k = 0; k < 8; ++k) {
            const int koff = k * 32 + q * 8;
            bf16x8 pf[4];
            #pragma unroll
            for (int p = 0; p < 4; ++p)
                pf[p] = *(const bf16x8*)&lds[((5 + p) * 16 + l15) * KPAD + koff];
            #pragma unroll
            for (int m = 0; m < 2; ++m) {
                const int mt = wave * 2 + m;
                bf16x8 ao = wof[(mt * 8 + k) * 64 + lane];
                #pragma unroll
                for (int p = 0; p < 4; ++p)
                    accB[m][p] = __builtin_amdgcn_mfma_f32_16x16x32_bf16(ao, pf[p], accB[m][p], 0, 0, 0);
            }
        }
        __syncthreads();   // all P reads done; scratch may overlay P

        // ---- Epilogue: per-wave LDS transpose -> fully coalesced f4 stores ----
        float* sf = (float*)(lds + wave * 4736);   // 9472 B per wave
        const int tok2 = lane >> 2, sub = lane & 3;
        #pragma unroll
        for (int m = 0; m < 2; ++m) {
            const int mt = wave * 2 + m;
            #pragma unroll
            for (int reg = 0; reg < 4; ++reg) {
                const int o9 = (q * 4 + reg) * 9;
                #pragma unroll
                for (int p = 0; p < 9; ++p) {
                    float v = (p < 5) ? accA[m][p][reg] : accB[m][p - 5][reg];
                    sf[l15 * 148 + o9 + p] = v;
                }
            }
            __syncthreads();   // scratch visible (also fences m=1 overwrite)
            float* wdst = out + ((size_t)g * 16 + tok2) * 2304 + mt * 144;
            #pragma unroll
            for (int it = 0; it < 9; ++it) {
                const int f4 = sub + 4 * it;
                float4 v = *(const float4*)&sf[tok2 * 148 + f4 * 4];
                ((float4*)wdst)[f4] = v;   // 16 full 64B lines per instr, no RMW
            }
            __syncthreads();   // reads done before next m / next iter overwrites

            // Issue next-group R prefetch after half the accumulators die:
            // live here ~= acc[1] (36) + preL (24) + preR (24) < cap.
            if (m == 0 && itg != GPB - 1) {
                #pragma unroll
                for (int u = 0; u < 6; ++u) preR[u] = R4[nbase + u * 512 + tid];
            }
        }
        g = gn;
    }
}

extern "C" void kernel_launch(void* const* d_in, const int* in_sizes, int n_in,
                              void* d_out, int out_size, void* d_ws, size_t ws_size,
                              hipStream_t stream) {
    const float* xl = (const float*)d_in[0];
    const float* xr = (const float*)d_in[1];
    const float* wl = (const float*)d_in[2];
    const float* wr = (const float*)d_in[3];
    const float* wo = (const float*)d_in[4];
    float* out = (float*)d_out;
    unsigned short* wsw = (unsigned short*)d_ws;   // 384 KB bf16 swizzled weights

    prep_weights<<<768, 256, 0, stream>>>(wl, wr, wo, wsw);
    fused_kernel<<<NBLK, 512, 0, stream>>>(xl, xr, wsw, out);
}

// Round 3
// 780.206 us; speedup vs baseline: 1.0000x; 1.0000x over previous
//
#include <hip/hip_runtime.h>

typedef short bf16x8 __attribute__((ext_vector_type(8)));
typedef float f32x4 __attribute__((ext_vector_type(4)));

__device__ inline unsigned short f2bf(float f) {
    union { float f; unsigned u; } v; v.f = f;
    unsigned u = v.u;
    u += 0x7fffu + ((u >> 16) & 1u);   // RNE
    return (unsigned short)(u >> 16);
}

#define KPAD 264   // 256 + 8 bf16 pad -> 2-way bank aliasing only (free)
#define GPB  4     // token-groups per persistent block
#define NBLK 512   // grid: exactly 2 blocks/CU on 256 CUs

// Swizzle W (fp32 [256][256] row-major) -> bf16 MFMA A-fragment order:
// wsw[((mt*8+ks)*64 + lane)*8 + jj] = W[mt*16 + (lane&15)][ks*32 + (lane>>4)*8 + jj]
__global__ void prep_weights(const float* __restrict__ wl,
                             const float* __restrict__ wr,
                             const float* __restrict__ wo,
                             unsigned short* __restrict__ wsw) {
    int idx = blockIdx.x * 256 + threadIdx.x;   // 0 .. 196607
    int w    = idx >> 16;
    int e    = idx & 65535;
    int jj   = e & 7;
    int lane = (e >> 3) & 63;
    int kmt  = e >> 9;          // mt*8 + ks
    int ks   = kmt & 7;
    int mt   = kmt >> 3;
    int row = mt * 16 + (lane & 15);
    int col = ks * 32 + (lane >> 4) * 8 + jj;
    const float* src = (w == 0) ? wl : (w == 1) ? wr : wo;
    wsw[idx] = f2bf(src[row * 256 + col]);
}

// Persistent: 512 blocks (2/CU), GPB=4 groups of 16 tokens each.
// Round-2 lesson: prefetch regs live across stage-2's peak (acc 72 + pf 20)
// spilled to scratch (+1 GB HBM). Fix: issue BOTH prefetches in the epilogue
// after the m=0 stores, where accA[0]/accB[0] are dead (live ~= 36 acc + 48
// pre + bases < 128). sched_barrier(0) pins them there.
__global__ __launch_bounds__(512, 4) void fused_kernel(
    const float* __restrict__ xl_g, const float* __restrict__ xr_g,
    const unsigned short* __restrict__ wsw, float* __restrict__ out) {

    // LDS per iteration: XB_l [48][KPAD] @0, XB_r @12672 (bf16) ->
    // P [144][KPAD] overlays @0 -> epilogue scratch 8 waves x 9472 B overlays P.
    __shared__ __align__(16) unsigned short lds[38016];

    const int tid  = threadIdx.x;
    const int wave = tid >> 6;
    const int lane = tid & 63;
    const int q    = lane >> 4;
    const int l15  = lane & 15;

    const float4* L4 = (const float4*)xl_g;
    const float4* R4 = (const float4*)xr_g;
    const bf16x8* wlf = (const bf16x8*)(wsw);
    const bf16x8* wrf = (const bf16x8*)(wsw + 65536);
    const bf16x8* wof = (const bf16x8*)(wsw + 131072);

    int g = blockIdx.x;                      // group index, stride NBLK per iter
    float4 preL[6], preR[6];                 // statically indexed only
    {
        const size_t base = (size_t)g * 3072;
        #pragma unroll
        for (int u = 0; u < 6; ++u) preL[u] = L4[base + u * 512 + tid];
        #pragma unroll
        for (int u = 0; u < 6; ++u) preR[u] = R4[base + u * 512 + tid];
    }

    for (int itg = 0; itg < GPB; ++itg) {

        // ---- Stage 0: prefetched regs -> LDS, fp32 -> bf16, c = i*16 + t ----
        #pragma unroll
        for (int a = 0; a < 2; ++a) {
            unsigned short* dst = lds + a * 12672;
            #pragma unroll
            for (int u = 0; u < 6; ++u) {
                float4 v = a ? preR[u] : preL[u];
                int g4 = u * 512 + tid;
                int gi = g4 * 4;             // 768 % 4 == 0: never straddles a token
                int tok = gi / 768;
                int m0 = gi - tok * 768;
                float vv[4] = {v.x, v.y, v.z, v.w};
                #pragma unroll
                for (int e = 0; e < 4; ++e) {
                    int mm = m0 + e;
                    int I = mm / 3;
                    int i = mm - I * 3;
                    dst[(i * 16 + tok) * KPAD + I] = f2bf(vv[e]);
                }
            }
        }
        __syncthreads();
        // preL/preR are DEAD here until the epilogue re-fills them: their 48
        // regs are free for stage-1/2 accumulators.

        // ---- Stage 1: xl = W_l * x_l, xr = W_r * x_r (two M-tiles per wave) ----
        f32x4 accL[2][3] = {};
        f32x4 accR[2][3] = {};
        #pragma unroll
        for (int k = 0; k < 8; ++k) {
            const int koff = k * 32 + q * 8;
            bf16x8 bl[3], br[3];
            #pragma unroll
            for (int nt = 0; nt < 3; ++nt) {
                bl[nt] = *(const bf16x8*)&lds[(nt * 16 + l15) * KPAD + koff];
                br[nt] = *(const bf16x8*)&lds[12672 + (nt * 16 + l15) * KPAD + koff];
            }
            #pragma unroll
            for (int m = 0; m < 2; ++m) {
                const int mt = wave * 2 + m;
                bf16x8 al = wlf[(mt * 8 + k) * 64 + lane];
                bf16x8 ar = wrf[(mt * 8 + k) * 64 + lane];
                #pragma unroll
                for (int nt = 0; nt < 3; ++nt) {
                    accL[m][nt] = __builtin_amdgcn_mfma_f32_16x16x32_bf16(al, bl[nt], accL[m][nt], 0, 0, 0);
                    accR[m][nt] = __builtin_amdgcn_mfma_f32_16x16x32_bf16(ar, br[nt], accR[m][nt], 0, 0, 0);
                }
            }
        }
        __syncthreads();   // all stage-1 LDS reads done; P may overlay XB

        // ---- P build: outer product in regs, write bf16 P[c=(i*3+j)*16+t][r] ----
        #pragma unroll
        for (int m = 0; m < 2; ++m) {
            const int mt = wave * 2 + m;
            const int r0 = mt * 16 + q * 4;
            #pragma unroll
            for (int i = 0; i < 3; ++i) {
                #pragma unroll
                for (int j = 0; j < 3; ++j) {
                    const int c = (i * 3 + j) * 16 + l15;
                    unsigned short h[4];
                    #pragma unroll
                    for (int reg = 0; reg < 4; ++reg)
                        h[reg] = f2bf(accL[m][i][reg] * accR[m][j][reg]);
                    uint2 pk;
                    pk.x = (unsigned)h[0] | ((unsigned)h[1] << 16);
                    pk.y = (unsigned)h[2] | ((unsigned)h[3] << 16);
                    *(uint2*)&lds[c * KPAD + r0] = pk;   // 8B aligned
                }
            }
        }
        __syncthreads();

        // ---- Stage 2: out = W_o * P (256 x 256 x 144), two k-passes ----
        f32x4 accA[2][5] = {};
        f32x4 accB[2][4] = {};
        #pragma unroll
        for (int k = 0; k < 8; ++k) {
            const int koff = k * 32 + q * 8;
            bf16x8 pf[5];
            #pragma unroll
            for (int p = 0; p < 5; ++p)
                pf[p] = *(const bf16x8*)&lds[(p * 16 + l15) * KPAD + koff];
            #pragma unroll
            for (int m = 0; m < 2; ++m) {
                const int mt = wave * 2 + m;
                bf16x8 ao = wof[(mt * 8 + k) * 64 + lane];
                #pragma unroll
                for (int p = 0; p < 5; ++p)
                    accA[m][p] = __builtin_amdgcn_mfma_f32_16x16x32_bf16(ao, pf[p], accA[m][p], 0, 0, 0);
            }
        }
        #pragma unroll
        for (int k = 0; k < 8; ++k) {
            const int koff = k * 32 + q * 8;
            bf16x8 pf[4];
            #pragma unroll
            for (int p = 0; p < 4; ++p)
                pf[p] = *(const bf16x8*)&lds[((5 + p) * 16 + l15) * KPAD + koff];
            #pragma unroll
            for (int m = 0; m < 2; ++m) {
                const int mt = wave * 2 + m;
                bf16x8 ao = wof[(mt * 8 + k) * 64 + lane];
                #pragma unroll
                for (int p = 0; p < 4; ++p)
                    accB[m][p] = __builtin_amdgcn_mfma_f32_16x16x32_bf16(ao, pf[p], accB[m][p], 0, 0, 0);
            }
        }
        __syncthreads();   // all P reads done; scratch may overlay P

        // ---- Epilogue: per-wave LDS transpose -> coalesced f4 stores ----
        // sf is WAVE-PRIVATE (lds + wave*4736): no block barriers needed inside;
        // per-wave DS ops are in-order (lgkmcnt) so write->read->overwrite is
        // safe within the wave. Waves desync their store bursts.
        float* sf = (float*)(lds + wave * 4736);   // 9472 B per wave
        const int tok2 = lane >> 2, sub = lane & 3;
        #pragma unroll
        for (int m = 0; m < 2; ++m) {
            const int mt = wave * 2 + m;
            #pragma unroll
            for (int reg = 0; reg < 4; ++reg) {
                const int o9 = (q * 4 + reg) * 9;
                #pragma unroll
                for (int p = 0; p < 9; ++p) {
                    float v = (p < 5) ? accA[m][p][reg] : accB[m][p - 5][reg];
                    sf[l15 * 148 + o9 + p] = v;
                }
            }
            float* wdst = out + ((size_t)g * 16 + tok2) * 2304 + mt * 144;
            #pragma unroll
            for (int it = 0; it < 9; ++it) {
                const int f4 = sub + 4 * it;
                float4 v = *(const float4*)&sf[tok2 * 148 + f4 * 4];
                ((float4*)wdst)[f4] = v;   // 16 full 64B lines per instr, no RMW
            }
            // Prefetch next group's x NOW: accA[0]/accB[0] are dead (36 live
            // acc + 48 pre + bases ~= 100 < 128). Loads hide under the m=1
            // transpose + stores (~1-2us >> HBM latency) and overlap the
            // store drain. sched_barrier pins them against hoisting into
            // stage 2 (which would re-create round-2's spill).
            if (m == 0 && itg != GPB - 1) {
                __builtin_amdgcn_sched_barrier(0);
                const size_t nbase = (size_t)(g + NBLK) * 3072;
                #pragma unroll
                for (int u = 0; u < 6; ++u) preL[u] = L4[nbase + u * 512 + tid];
                #pragma unroll
                for (int u = 0; u < 6; ++u) preR[u] = R4[nbase + u * 512 + tid];
                __builtin_amdgcn_sched_barrier(0);
            }
        }
        __syncthreads();   // all sf reads done before next stage0 overwrites LDS
        g += NBLK;
    }
}

extern "C" void kernel_launch(void* const* d_in, const int* in_sizes, int n_in,
                              void* d_out, int out_size, void* d_ws, size_t ws_size,
                              hipStream_t stream) {
    const float* xl = (const float*)d_in[0];
    const float* xr = (const float*)d_in[1];
    const float* wl = (const float*)d_in[2];
    const float* wr = (const float*)d_in[3];
    const float* wo = (const float*)d_in[4];
    float* out = (float*)d_out;
    unsigned short* wsw = (unsigned short*)d_ws;   // 384 KB bf16 swizzled weights

    prep_weights<<<768, 256, 0, stream>>>(wl, wr, wo, wsw);
    fused_kernel<<<NBLK, 512, 0, stream>>>(xl, xr, wsw, out);
}

// Round 4
// 501.771 us; speedup vs baseline: 1.5549x; 1.5549x over previous
//
#include <hip/hip_runtime.h>

typedef short bf16x8 __attribute__((ext_vector_type(8)));
typedef float f32x4 __attribute__((ext_vector_type(4)));

__device__ inline unsigned short f2bf(float f) {
    union { float f; unsigned u; } v; v.f = f;
    unsigned u = v.u;
    u += 0x7fffu + ((u >> 16) & 1u);   // RNE
    return (unsigned short)(u >> 16);
}

// T2 XOR swizzle: row stride 256 shorts (512 B == 0 mod 32 banks) + XOR of
// row&7 into bits 3..5 of the in-row short index. Every ds_read_b128 with
// rows varying by lane lands 8 lanes per 4-bank group (uniform, free 2-way).
// s < 256, XOR stays < 256; 8-short (16B) and 4-short (8B) alignment is
// preserved (XOR touches bits >= 3 only... bit3 flips 8B blocks, keeps 4- and
// 8-short multiples).
#define SWZ(row, s) (((row) << 8) | ((s) ^ (((row) & 7) << 3)))

// Swizzle W (fp32 [256][256] row-major) -> bf16 MFMA A-fragment order:
// wsw[((mt*8+ks)*64 + lane)*8 + jj] = W[mt*16 + (lane&15)][ks*32 + (lane>>4)*8 + jj]
__global__ void prep_weights(const float* __restrict__ wl,
                             const float* __restrict__ wr,
                             const float* __restrict__ wo,
                             unsigned short* __restrict__ wsw) {
    int idx = blockIdx.x * 256 + threadIdx.x;   // 0 .. 196607
    int w    = idx >> 16;
    int e    = idx & 65535;
    int jj   = e & 7;
    int lane = (e >> 3) & 63;
    int kmt  = e >> 9;          // mt*8 + ks
    int ks   = kmt & 7;
    int mt   = kmt >> 3;
    int row = mt * 16 + (lane & 15);
    int col = ks * 32 + (lane >> 4) * 8 + jj;
    const float* src = (w == 0) ? wl : (w == 1) ? wr : wo;
    wsw[idx] = f2bf(src[row * 256 + col]);
}

// Non-persistent (round-1 structure, best measured): 2048 blocks x 16 tokens.
// 512 threads = 8 waves, 2 M-tiles/wave. launch_bounds(512,4) -> 128-reg cap,
// 2 blocks/CU (LDS 75776 B also caps at 2). Rounds 2-3 showed persistent +
// register prefetch spills ~500 MB of scratch each way -> reverted.
__global__ __launch_bounds__(512, 4) void fused_kernel(
    const float* __restrict__ xl_g, const float* __restrict__ xr_g,
    const unsigned short* __restrict__ wsw, float* __restrict__ out) {

    // LDS states: XB_l [48][256] @0, XB_r @12288 (bf16, swizzled) ->
    // P [144][256] overlays @0 (73728 B) -> epilogue scratch 8 x 9472 B.
    __shared__ __align__(16) unsigned short lds[37888];

    const int tid  = threadIdx.x;
    const int blk  = blockIdx.x;
    const int wave = tid >> 6;
    const int lane = tid & 63;
    const int q    = lane >> 4;
    const int l15  = lane & 15;

    // ---- Stage 0: 12-float groups -> 3x ds_write_b64 per group ------------
    // Group G (0..1023 per side) = token G>>6, channels I0=4*(G&63)..I0+3,
    // all 3 spatial i. 12 consecutive floats = 3 aligned float4 loads.
    // Thread handles G = tid and G = 512+tid for both sides (12 loads total,
    // issued up-front so both sides' HBM latency overlaps).
    {
        const float4* p0 = (const float4*)(xl_g + (size_t)blk * 12288);
        const float4* p1 = (const float4*)(xr_g + (size_t)blk * 12288);
        const int tok0 = tid >> 6;          // == wave
        const int tok1 = 8 + tok0;
        const int c0   = tid & 63;          // group-in-token; same for both sweeps
        const int I0   = c0 * 4;
        float4 ld[12];
        #pragma unroll
        for (int u = 0; u < 3; ++u) ld[u]     = p0[tok0 * 192 + c0 * 3 + u];
        #pragma unroll
        for (int u = 0; u < 3; ++u) ld[3 + u] = p0[tok1 * 192 + c0 * 3 + u];
        #pragma unroll
        for (int u = 0; u < 3; ++u) ld[6 + u] = p1[tok0 * 192 + c0 * 3 + u];
        #pragma unroll
        for (int u = 0; u < 3; ++u) ld[9 + u] = p1[tok1 * 192 + c0 * 3 + u];
        #pragma unroll
        for (int a = 0; a < 2; ++a) {
            unsigned short* dst = lds + a * 12288;
            #pragma unroll
            for (int s = 0; s < 2; ++s) {
                const int tok = s ? tok1 : tok0;
                float f[12];
                #pragma unroll
                for (int u = 0; u < 3; ++u) {
                    float4 v = ld[a * 6 + s * 3 + u];
                    f[u * 4 + 0] = v.x; f[u * 4 + 1] = v.y;
                    f[u * 4 + 2] = v.z; f[u * 4 + 3] = v.w;
                }
                // f[j]: channel I = I0 + j/3, spatial i = j%3.
                #pragma unroll
                for (int c = 0; c < 3; ++c) {
                    const int row = c * 16 + tok;
                    uint2 pk;
                    pk.x = (unsigned)f2bf(f[c])     | ((unsigned)f2bf(f[3 + c]) << 16);
                    pk.y = (unsigned)f2bf(f[6 + c]) | ((unsigned)f2bf(f[9 + c]) << 16);
                    *(uint2*)&dst[SWZ(row, I0)] = pk;   // 4 shorts I0..I0+3, 8B aligned
                }
            }
        }
    }
    __syncthreads();

    // ---- Stage 1: xl = W_l * x_l, xr = W_r * x_r (two M-tiles per wave) ----
    const bf16x8* wlf = (const bf16x8*)(wsw);
    const bf16x8* wrf = (const bf16x8*)(wsw + 65536);
    const bf16x8* wof = (const bf16x8*)(wsw + 131072);

    f32x4 accL[2][3] = {};
    f32x4 accR[2][3] = {};
    #pragma unroll
    for (int k = 0; k < 8; ++k) {
        const int koff = k * 32 + q * 8;
        bf16x8 bl[3], br[3];
        #pragma unroll
        for (int nt = 0; nt < 3; ++nt) {
            const int row = nt * 16 + l15;
            bl[nt] = *(const bf16x8*)&lds[SWZ(row, koff)];
            br[nt] = *(const bf16x8*)&lds[12288 + SWZ(row, koff)];
        }
        #pragma unroll
        for (int m = 0; m < 2; ++m) {
            const int mt = wave * 2 + m;
            bf16x8 al = wlf[(mt * 8 + k) * 64 + lane];
            bf16x8 ar = wrf[(mt * 8 + k) * 64 + lane];
            #pragma unroll
            for (int nt = 0; nt < 3; ++nt) {
                accL[m][nt] = __builtin_amdgcn_mfma_f32_16x16x32_bf16(al, bl[nt], accL[m][nt], 0, 0, 0);
                accR[m][nt] = __builtin_amdgcn_mfma_f32_16x16x32_bf16(ar, br[nt], accR[m][nt], 0, 0, 0);
            }
        }
    }
    __syncthreads();   // all stage-1 LDS reads done; P may overlay XB

    // ---- P build: outer product in regs, write bf16 P[c=(i*3+j)*16+t][r] ----
    #pragma unroll
    for (int m = 0; m < 2; ++m) {
        const int mt = wave * 2 + m;
        const int r0 = mt * 16 + q * 4;      // this lane's 4 consecutive r
        #pragma unroll
        for (int i = 0; i < 3; ++i) {
            #pragma unroll
            for (int j = 0; j < 3; ++j) {
                const int c = (i * 3 + j) * 16 + l15;
                unsigned short h[4];
                #pragma unroll
                for (int reg = 0; reg < 4; ++reg)
                    h[reg] = f2bf(accL[m][i][reg] * accR[m][j][reg]);
                uint2 pk;
                pk.x = (unsigned)h[0] | ((unsigned)h[1] << 16);
                pk.y = (unsigned)h[2] | ((unsigned)h[3] << 16);
                *(uint2*)&lds[SWZ(c, r0)] = pk;   // 8B aligned (XOR bits >=3)
            }
        }
    }
    __syncthreads();

    // ---- Stage 2: out = W_o * P (256 x 256 x 144), two k-passes ------------
    f32x4 accA[2][5] = {};
    f32x4 accB[2][4] = {};
    #pragma unroll
    for (int k = 0; k < 8; ++k) {
        const int koff = k * 32 + q * 8;
        bf16x8 pf[5];
        #pragma unroll
        for (int p = 0; p < 5; ++p)
            pf[p] = *(const bf16x8*)&lds[SWZ(p * 16 + l15, koff)];
        #pragma unroll
        for (int m = 0; m < 2; ++m) {
            const int mt = wave * 2 + m;
            bf16x8 ao = wof[(mt * 8 + k) * 64 + lane];
            #pragma unroll
            for (int p = 0; p < 5; ++p)
                accA[m][p] = __builtin_amdgcn_mfma_f32_16x16x32_bf16(ao, pf[p], accA[m][p], 0, 0, 0);
        }
    }
    #pragma unroll
    for (int k = 0; k < 8; ++k) {
        const int koff = k * 32 + q * 8;
        bf16x8 pf[4];
        #pragma unroll
        for (int p = 0; p < 4; ++p)
            pf[p] = *(const bf16x8*)&lds[SWZ((5 + p) * 16 + l15, koff)];
        #pragma unroll
        for (int m = 0; m < 2; ++m) {
            const int mt = wave * 2 + m;
            bf16x8 ao = wof[(mt * 8 + k) * 64 + lane];
            #pragma unroll
            for (int p = 0; p < 4; ++p)
                accB[m][p] = __builtin_amdgcn_mfma_f32_16x16x32_bf16(ao, pf[p], accB[m][p], 0, 0, 0);
        }
    }
    __syncthreads();   // all P reads done; scratch may overlay P

    // ---- Epilogue: per-wave LDS transpose -> fully coalesced f4 stores -----
    // Lane's 36 results are flat-contiguous in scratch: q*36 + reg*9 + p
    // -> 9 ds_write_b128 (stride 148 f32: 37 dw ~ 5 mod 8 -> uniform banks).
    // Reads: tok=lane>>2, sub=lane&3 -> each store instr = 16 full 64B lines.
    // Scratch is wave-private: no block barriers needed inside (per-wave DS
    // ordering; proven correct in rounds 1-3).
    float* sfw = (float*)lds + wave * 2368;   // 16 x 148 floats = 9472 B
    const int tok2 = lane >> 2, sub = lane & 3;
    #pragma unroll
    for (int m = 0; m < 2; ++m) {
        const int mt = wave * 2 + m;
        float vf[36];
        #pragma unroll
        for (int reg = 0; reg < 4; ++reg)
            #pragma unroll
            for (int p = 0; p < 9; ++p)
                vf[reg * 9 + p] = (p < 5) ? accA[m][p][reg] : accB[m][p - 5][reg];
        float* wbase = sfw + l15 * 148 + q * 36;   // 16B aligned (148,36 div 4)
        #pragma unroll
        for (int w = 0; w < 9; ++w) {
            float4 t;
            t.x = vf[4 * w]; t.y = vf[4 * w + 1];
            t.z = vf[4 * w + 2]; t.w = vf[4 * w + 3];
            *(float4*)&wbase[4 * w] = t;
        }
        float* wdst = out + ((size_t)blk * 16 + tok2) * 2304 + mt * 144;
        #pragma unroll
        for (int it = 0; it < 9; ++it) {
            const int f4i = sub + 4 * it;
            float4 v = *(const float4*)&sfw[tok2 * 148 + f4i * 4];
            ((float4*)wdst)[f4i] = v;   // 576 B contiguous per (tok,mt), no RMW
        }
    }
}

extern "C" void kernel_launch(void* const* d_in, const int* in_sizes, int n_in,
                              void* d_out, int out_size, void* d_ws, size_t ws_size,
                              hipStream_t stream) {
    const float* xl = (const float*)d_in[0];
    const float* xr = (const float*)d_in[1];
    const float* wl = (const float*)d_in[2];
    const float* wr = (const float*)d_in[3];
    const float* wo = (const float*)d_in[4];
    float* out = (float*)d_out;
    unsigned short* wsw = (unsigned short*)d_ws;   // 384 KB bf16 swizzled weights

    prep_weights<<<768, 256, 0, stream>>>(wl, wr, wo, wsw);
    fused_kernel<<<2048, 512, 0, stream>>>(xl, xr, wsw, out);
}